// Round 5
// baseline (10553.831 us; speedup 1.0000x reference)
//
#include <hip/hip_runtime.h>
#include <hip/hip_bf16.h>

#define BB 64
#define SS 512
#define HH 1024
#define G4 4096

using bf8_t = __attribute__((ext_vector_type(8))) short;   // 8 bf16 (4 VGPRs)
using f32x4 = __attribute__((ext_vector_type(4))) float;   // 4 fp32 acc

__device__ inline ushort f2bf(float f) {
  __hip_bfloat16 h = __float2bfloat16(f);
  return *reinterpret_cast<ushort*>(&h);
}
__device__ inline float bf2f(ushort u) {
  unsigned v = ((unsigned)u) << 16;
  return __uint_as_float(v);
}

// fp32 [R][C] -> bf16 [C][R]
__global__ __launch_bounds__(256) void k_transpose_cast(
    const float* __restrict__ in, ushort* __restrict__ out, int R, int C) {
  __shared__ float tile[32][33];
  int c0 = blockIdx.x * 32, r0 = blockIdx.y * 32;
  int tx = threadIdx.x & 31, ty = threadIdx.x >> 5;  // 32 x 8
  for (int i = ty; i < 32; i += 8) {
    int r = r0 + i, c = c0 + tx;
    tile[i][tx] = (r < R && c < C) ? in[(size_t)r * C + c] : 0.f;
  }
  __syncthreads();
  for (int i = ty; i < 32; i += 8) {
    int c = c0 + i, r = r0 + tx;
    if (c < C && r < R) out[(size_t)c * R + r] = f2bf(tile[tx][i]);
  }
}

// Ae[row = t*64+b][k] = embed_tok[x[b][t]][k] + embed_pos[t][k], bf16
__global__ __launch_bounds__(256) void k_embed(
    const int* __restrict__ x, const float* __restrict__ etok,
    const float* __restrict__ epos, ushort* __restrict__ Ae) {
  int row = blockIdx.x;
  int t = row >> 6, b = row & 63;
  int tok = x[b * SS + t];
  const float4* tp = (const float4*)(etok + (size_t)tok * HH);
  const float4* pp = (const float4*)(epos + (size_t)t * HH);
  int i = threadIdx.x;  // 256 threads * float4 = 1024
  float4 a = tp[i], p = pp[i];
  ushort4 r = make_ushort4(f2bf(a.x + p.x), f2bf(a.y + p.y),
                           f2bf(a.z + p.z), f2bf(a.w + p.w));
  ((ushort4*)(Ae + (size_t)row * HH))[i] = r;
}

// C[m][n] (bf16) = A[m][k] @ Bt[n][k]^T + bias[n].  M,N mult of 128, K=1024.
__global__ __launch_bounds__(256) void k_gemm_xi(
    const ushort* __restrict__ Ag, const ushort* __restrict__ Bt,
    const float* __restrict__ bias, ushort* __restrict__ Cout, int N) {
  __shared__ alignas(16) ushort As[128 * 40];   // rows padded 32->40 shorts
  __shared__ alignas(16) ushort Bs[128 * 40];
  const int m0 = blockIdx.y * 128, n0 = blockIdx.x * 128;
  const int tid = threadIdx.x;
  const int srow = tid >> 1, shalf = tid & 1;   // stage: 2 thr/row, 16 shorts each
  const int w = tid >> 6, lane = tid & 63;
  const int wm = w >> 1, wn = w & 1;            // 2x2 waves, 64x64 each
  const int lr = lane & 15, kq = lane >> 4;
  f32x4 acc[4][4] = {};
  for (int k0 = 0; k0 < HH; k0 += 32) {
    const uint4* ga = (const uint4*)(Ag + (size_t)(m0 + srow) * HH + k0 + shalf * 16);
    const uint4* gb = (const uint4*)(Bt + (size_t)(n0 + srow) * HH + k0 + shalf * 16);
    uint4 va0 = ga[0], va1 = ga[1];
    uint4 vb0 = gb[0], vb1 = gb[1];
    __syncthreads();
    *(uint4*)&As[srow * 40 + shalf * 16]     = va0;
    *(uint4*)&As[srow * 40 + shalf * 16 + 8] = va1;
    *(uint4*)&Bs[srow * 40 + shalf * 16]     = vb0;
    *(uint4*)&Bs[srow * 40 + shalf * 16 + 8] = vb1;
    __syncthreads();
    bf8_t fa[4], fb[4];
#pragma unroll
    for (int i = 0; i < 4; ++i) {
      fa[i] = *(const bf8_t*)&As[(wm * 64 + i * 16 + lr) * 40 + kq * 8];
      fb[i] = *(const bf8_t*)&Bs[(wn * 64 + i * 16 + lr) * 40 + kq * 8];
    }
#pragma unroll
    for (int mi = 0; mi < 4; ++mi)
#pragma unroll
      for (int ni = 0; ni < 4; ++ni)
        acc[mi][ni] = __builtin_amdgcn_mfma_f32_16x16x32_bf16(fa[mi], fb[ni], acc[mi][ni], 0, 0, 0);
  }
#pragma unroll
  for (int mi = 0; mi < 4; ++mi) {
    int grow = m0 + wm * 64 + mi * 16 + kq * 4;
#pragma unroll
    for (int ni = 0; ni < 4; ++ni) {
      int gcol = n0 + wn * 64 + ni * 16 + lr;
      float bv = bias[gcol];
#pragma unroll
      for (int r = 0; r < 4; ++r)
        Cout[(size_t)(grow + r) * N + gcol] = f2bf(acc[mi][ni][r] + bv);
    }
  }
}

// Persistent recurrence, 4 independent batch groups x 64 column-owner WGs.
// Sync = C++ release/acquire via compiler fences, amortized to one
// fence(RELEASE)+one fence(ACQUIRE) per WG per step; polls are RELAXED
// (no per-iteration cache maintenance). h tile staged into LDS per step
// (two 16KB halves); Wh slice resident in LDS; c in wave-0 regs.
__global__ __launch_bounds__(256, 1) void k_recur(
    const ushort* __restrict__ Wh_t,   // [4096][1024] bf16
    const ushort* __restrict__ xi,     // [S*64][4096] bf16 (bh folded in)
    ushort* __restrict__ hs,           // [(S+1)*64][1024] bf16, hs[0]=0
    unsigned* __restrict__ arrive) {   // [4][64] monotonic step counters
  __shared__ alignas(16) ushort Wlds[64 * 1024];   // 128 KiB
  __shared__ alignas(16) ushort htile[16 * 512];   // 16 KiB (one K-half)
  __shared__ alignas(16) float zbuf[4][16][20];    // 5 KiB
  const int grp = blockIdx.x >> 6;      // batch group 0..3
  const int mem = blockIdx.x & 63;      // member in group (column owner)
  const int n0 = mem * 16;
  const int brow0 = grp * 16;
  const int tid = threadIdx.x;
  unsigned* slot = arrive + grp * 64;

  // one-time stage of Wh slice, swizzled: unit u = row*128 + (k16 ^ (row&7))
  for (int s = tid; s < 64 * 128; s += 256) {
    int row = s >> 7, k16 = s & 127;
    int g = row >> 4, j = row & 15;
    uint4 v = *(const uint4*)(Wh_t + (size_t)(g * 1024 + n0 + j) * HH + k16 * 8);
    *(uint4*)&Wlds[(row * 128 + (k16 ^ (row & 7))) * 8] = v;
  }
  __syncthreads();

  const int w = tid >> 6, lane = tid & 63;
  const int lr = lane & 15, kq = lane >> 4;
  // h staging: thread owns row srow, 8 contiguous 16B units at k-chunk scol
  const int srow = tid >> 4, scol = tid & 15;
  const int sphase = scol >> 3;                    // which K-half these go to
  ushort* wdst = &htile[((srow * 64) + ((scol & 7) * 8)) * 8];
  const int rx = srow & 7;
  // epilogue (wave 0 only): lane owns (eb, en4..en4+3)
  const int eb = lane >> 2, en4 = (lane & 3) * 4;
  float cr[4] = {0.f, 0.f, 0.f, 0.f};

  for (int t = 0; t < SS; ++t) {
    // ---- load h tile (plain loads; 8 independent -> overlapped) ----
    const ushort* hbase = hs + (size_t)t * BB * HH +
                          (size_t)(brow0 + srow) * HH + scol * 64;
    uint4 hv[8];
#pragma unroll
    for (int i = 0; i < 8; ++i) hv[i] = *(const uint4*)(hbase + i * 8);
    ushort4 xv[4] = {};
    if (w == 0) {   // xi for epilogue: 4 gates x 4 cols (8B each)
      const ushort* xb = xi + ((size_t)t * 64 + brow0 + eb) * G4 + n0 + en4;
#pragma unroll
      for (int g = 0; g < 4; ++g) xv[g] = *(const ushort4*)(xb + (size_t)g * 1024);
    }

    // ---- phase 0: stage K-half 0, compute chunks 0..15 ----
    if (sphase == 0) {
#pragma unroll
      for (int i = 0; i < 8; ++i) *(uint4*)&wdst[(i ^ rx) * 8] = hv[i];
    }
    __syncthreads();
    f32x4 acc0 = {}, acc1 = {};
#pragma unroll
    for (int k = 0; k < 16; k += 2) {
      bf8_t fb0 = *(const bf8_t*)&Wlds[((w * 16 + lr) * 128 + ((k * 4 + kq) ^ (lr & 7))) * 8];
      bf8_t fa0 = *(const bf8_t*)&htile[(lr * 64 + ((k * 4 + kq) ^ (lr & 7))) * 8];
      bf8_t fb1 = *(const bf8_t*)&Wlds[((w * 16 + lr) * 128 + ((k * 4 + 4 + kq) ^ (lr & 7))) * 8];
      bf8_t fa1 = *(const bf8_t*)&htile[(lr * 64 + ((k * 4 + 4 + kq) ^ (lr & 7))) * 8];
      acc0 = __builtin_amdgcn_mfma_f32_16x16x32_bf16(fa0, fb0, acc0, 0, 0, 0);
      acc1 = __builtin_amdgcn_mfma_f32_16x16x32_bf16(fa1, fb1, acc1, 0, 0, 0);
    }
    __syncthreads();

    // ---- phase 1: stage K-half 1, compute chunks 16..31 ----
    if (sphase == 1) {
#pragma unroll
      for (int i = 0; i < 8; ++i) *(uint4*)&wdst[(i ^ rx) * 8] = hv[i];
    }
    __syncthreads();
#pragma unroll
    for (int k = 0; k < 16; k += 2) {
      bf8_t fb0 = *(const bf8_t*)&Wlds[((w * 16 + lr) * 128 + (((16 + k) * 4 + kq) ^ (lr & 7))) * 8];
      bf8_t fa0 = *(const bf8_t*)&htile[(lr * 64 + ((k * 4 + kq) ^ (lr & 7))) * 8];
      bf8_t fb1 = *(const bf8_t*)&Wlds[((w * 16 + lr) * 128 + (((16 + k) * 4 + 4 + kq) ^ (lr & 7))) * 8];
      bf8_t fa1 = *(const bf8_t*)&htile[(lr * 64 + ((k * 4 + 4 + kq) ^ (lr & 7))) * 8];
      acc0 = __builtin_amdgcn_mfma_f32_16x16x32_bf16(fa0, fb0, acc0, 0, 0, 0);
      acc1 = __builtin_amdgcn_mfma_f32_16x16x32_bf16(fa1, fb1, acc1, 0, 0, 0);
    }
#pragma unroll
    for (int r = 0; r < 4; ++r)
      zbuf[w][kq * 4 + r][lr] = acc0[r] + acc1[r];
    __syncthreads();

    // ---- epilogue (wave 0): gates, c update, h store ----
    if (w == 0) {
      f32x4 zi4 = *(const f32x4*)&zbuf[0][eb][en4];
      f32x4 zf4 = *(const f32x4*)&zbuf[1][eb][en4];
      f32x4 zg4 = *(const f32x4*)&zbuf[2][eb][en4];
      f32x4 zo4 = *(const f32x4*)&zbuf[3][eb][en4];
      ushort4 ho;
      ushort* hop = (ushort*)&ho;
#pragma unroll
      for (int j = 0; j < 4; ++j) {
        float zi = zi4[j] + bf2f(((const ushort*)&xv[0])[j]);
        float zf = zf4[j] + bf2f(((const ushort*)&xv[1])[j]);
        float zg = zg4[j] + bf2f(((const ushort*)&xv[2])[j]);
        float zo = zo4[j] + bf2f(((const ushort*)&xv[3])[j]);
        float si = 1.f / (1.f + __expf(-zi));
        float sf = 1.f / (1.f + __expf(-zf));
        float tg = tanhf(zg);
        float so = 1.f / (1.f + __expf(-zo));
        float c = sf * cr[j] + si * tg;
        cr[j] = c;
        hop[j] = f2bf(so * tanhf(c));
      }
      *(ushort4*)(hs + (size_t)(t + 1) * BB * HH +
                  (size_t)(brow0 + eb) * HH + n0 + en4) = ho;
    }

    if (t + 1 < SS) {
      if (w == 0) {
        // release: ONE wbl2+waitcnt for this step's h stores, then relaxed flag
        __builtin_amdgcn_fence(__ATOMIC_RELEASE, "agent");
        if (lane == 0)
          __hip_atomic_store(slot + mem, (unsigned)(t + 1), __ATOMIC_RELAXED,
                             __HIP_MEMORY_SCOPE_AGENT);
        // relaxed poll: lane l watches member l (no cache maintenance per iter)
        while (__hip_atomic_load(slot + lane, __ATOMIC_RELAXED,
                                 __HIP_MEMORY_SCOPE_AGENT) < (unsigned)(t + 1))
          __builtin_amdgcn_s_sleep(1);
      }
      __syncthreads();
      // acquire: ONE inv per wave; orders next iteration's h loads
      __builtin_amdgcn_fence(__ATOMIC_ACQUIRE, "agent");
    }
  }
}

// logits[b][t][a] = hs[t+1][b][:] . Wd_t[a][:] + bd[a]
__global__ __launch_bounds__(256) void k_logits(
    const ushort* __restrict__ hs1, const ushort* __restrict__ Wdt,
    const float* __restrict__ bd, float* __restrict__ out) {
  int gid = blockIdx.x * 256 + threadIdx.x;
  int a = gid & 15, row = gid >> 4;   // row = t*64+b
  int t = row >> 6, b = row & 63;
  const uint4* hp = (const uint4*)(hs1 + (size_t)row * HH);
  const uint4* wp = (const uint4*)(Wdt + (size_t)a * HH);
  float sum = 0.f;
#pragma unroll 4
  for (int i = 0; i < HH / 8; ++i) {
    uint4 hv = hp[i], wv = wp[i];
    const uint* hu = (const uint*)&hv;
    const uint* wu = (const uint*)&wv;
#pragma unroll
    for (int j = 0; j < 4; ++j) {
      sum += bf2f((ushort)(hu[j] & 0xffff)) * bf2f((ushort)(wu[j] & 0xffff));
      sum += bf2f((ushort)(hu[j] >> 16)) * bf2f((ushort)(wu[j] >> 16));
    }
  }
  out[32768 + ((size_t)b * SS + t) * 16 + a] = sum + bd[a];
}

extern "C" void kernel_launch(void* const* d_in, const int* in_sizes, int n_in,
                              void* d_out, int out_size, void* d_ws, size_t ws_size,
                              hipStream_t stream) {
  const int*   x    = (const int*)d_in[0];
  const float* etok = (const float*)d_in[4];
  const float* epos = (const float*)d_in[5];
  const float* Wi   = (const float*)d_in[6];
  const float* Wh   = (const float*)d_in[7];
  const float* bh   = (const float*)d_in[8];
  const float* Wd   = (const float*)d_in[9];
  const float* bd   = (const float*)d_in[10];

  char* ws = (char*)d_ws;
  size_t off = 0;
  ushort* Wi_t = (ushort*)(ws + off); off += (size_t)G4 * HH * 2;            // 8 MB
  ushort* Wh_t = (ushort*)(ws + off); off += (size_t)G4 * HH * 2;            // 8 MB
  ushort* Wd_t = (ushort*)(ws + off); off += 65536;                          // 32 KB (padded)
  ushort* Ae   = (ushort*)(ws + off); off += (size_t)BB * SS * HH * 2;       // 64 MB
  ushort* xi   = (ushort*)(ws + off); off += (size_t)BB * SS * G4 * 2;       // 256 MB
  ushort* hs   = (ushort*)(ws + off); off += (size_t)(SS + 1) * BB * HH * 2; // 64.1 MB
  unsigned* arrive = (unsigned*)(ws + off); off += 4096;

  hipMemsetAsync(d_out, 0, (size_t)out_size * 4, stream);          // dummies = 0
  hipMemsetAsync(hs, 0, (size_t)BB * HH * 2, stream);              // h_0 = 0
  hipMemsetAsync(arrive, 0, 4096, stream);                         // barrier slots

  dim3 b256(256);
  k_transpose_cast<<<dim3(G4 / 32, HH / 32), b256, 0, stream>>>(Wi, Wi_t, HH, G4);
  k_transpose_cast<<<dim3(G4 / 32, HH / 32), b256, 0, stream>>>(Wh, Wh_t, HH, G4);
  k_transpose_cast<<<dim3(1, HH / 32), b256, 0, stream>>>(Wd, Wd_t, HH, 16);
  k_embed<<<BB * SS, b256, 0, stream>>>(x, etok, epos, Ae);
  k_gemm_xi<<<dim3(G4 / 128, BB * SS / 128), b256, 0, stream>>>(Ae, Wi_t, bh, xi, G4);
  k_recur<<<256, b256, 0, stream>>>(Wh_t, xi, hs, arrive);
  k_logits<<<BB * SS * 16 / 256, b256, 0, stream>>>(hs + (size_t)BB * HH, Wd_t, bd,
                                                    (float*)d_out);
}

// Round 6
// 4218.584 us; speedup vs baseline: 2.5017x; 2.5017x over previous
//
#include <hip/hip_runtime.h>
#include <hip/hip_bf16.h>

#define BB 64
#define SS 512
#define HH 1024
#define G4 4096

using bf8_t = __attribute__((ext_vector_type(8))) short;   // 8 bf16 (4 VGPRs)
using f32x4 = __attribute__((ext_vector_type(4))) float;   // 4 fp32 acc

__device__ inline ushort f2bf(float f) {
  __hip_bfloat16 h = __float2bfloat16(f);
  return *reinterpret_cast<ushort*>(&h);
}
__device__ inline float bf2f(ushort u) {
  unsigned v = ((unsigned)u) << 16;
  return __uint_as_float(v);
}

// fp32 [R][C] -> bf16 [C][R]
__global__ __launch_bounds__(256) void k_transpose_cast(
    const float* __restrict__ in, ushort* __restrict__ out, int R, int C) {
  __shared__ float tile[32][33];
  int c0 = blockIdx.x * 32, r0 = blockIdx.y * 32;
  int tx = threadIdx.x & 31, ty = threadIdx.x >> 5;  // 32 x 8
  for (int i = ty; i < 32; i += 8) {
    int r = r0 + i, c = c0 + tx;
    tile[i][tx] = (r < R && c < C) ? in[(size_t)r * C + c] : 0.f;
  }
  __syncthreads();
  for (int i = ty; i < 32; i += 8) {
    int c = c0 + i, r = r0 + tx;
    if (c < C && r < R) out[(size_t)c * R + r] = f2bf(tile[tx][i]);
  }
}

// Ae[row = t*64+b][k] = embed_tok[x[b][t]][k] + embed_pos[t][k], bf16
__global__ __launch_bounds__(256) void k_embed(
    const int* __restrict__ x, const float* __restrict__ etok,
    const float* __restrict__ epos, ushort* __restrict__ Ae) {
  int row = blockIdx.x;
  int t = row >> 6, b = row & 63;
  int tok = x[b * SS + t];
  const float4* tp = (const float4*)(etok + (size_t)tok * HH);
  const float4* pp = (const float4*)(epos + (size_t)t * HH);
  int i = threadIdx.x;  // 256 threads * float4 = 1024
  float4 a = tp[i], p = pp[i];
  ushort4 r = make_ushort4(f2bf(a.x + p.x), f2bf(a.y + p.y),
                           f2bf(a.z + p.z), f2bf(a.w + p.w));
  ((ushort4*)(Ae + (size_t)row * HH))[i] = r;
}

// C[m][n] (bf16) = A[m][k] @ Bt[n][k]^T + bias[n].  M,N mult of 128, K=1024.
__global__ __launch_bounds__(256) void k_gemm_xi(
    const ushort* __restrict__ Ag, const ushort* __restrict__ Bt,
    const float* __restrict__ bias, ushort* __restrict__ Cout, int N) {
  __shared__ alignas(16) ushort As[128 * 40];   // rows padded 32->40 shorts
  __shared__ alignas(16) ushort Bs[128 * 40];
  const int m0 = blockIdx.y * 128, n0 = blockIdx.x * 128;
  const int tid = threadIdx.x;
  const int srow = tid >> 1, shalf = tid & 1;   // stage: 2 thr/row, 16 shorts each
  const int w = tid >> 6, lane = tid & 63;
  const int wm = w >> 1, wn = w & 1;            // 2x2 waves, 64x64 each
  const int lr = lane & 15, kq = lane >> 4;
  f32x4 acc[4][4] = {};
  for (int k0 = 0; k0 < HH; k0 += 32) {
    const uint4* ga = (const uint4*)(Ag + (size_t)(m0 + srow) * HH + k0 + shalf * 16);
    const uint4* gb = (const uint4*)(Bt + (size_t)(n0 + srow) * HH + k0 + shalf * 16);
    uint4 va0 = ga[0], va1 = ga[1];
    uint4 vb0 = gb[0], vb1 = gb[1];
    __syncthreads();
    *(uint4*)&As[srow * 40 + shalf * 16]     = va0;
    *(uint4*)&As[srow * 40 + shalf * 16 + 8] = va1;
    *(uint4*)&Bs[srow * 40 + shalf * 16]     = vb0;
    *(uint4*)&Bs[srow * 40 + shalf * 16 + 8] = vb1;
    __syncthreads();
    bf8_t fa[4], fb[4];
#pragma unroll
    for (int i = 0; i < 4; ++i) {
      fa[i] = *(const bf8_t*)&As[(wm * 64 + i * 16 + lr) * 40 + kq * 8];
      fb[i] = *(const bf8_t*)&Bs[(wn * 64 + i * 16 + lr) * 40 + kq * 8];
    }
#pragma unroll
    for (int mi = 0; mi < 4; ++mi)
#pragma unroll
      for (int ni = 0; ni < 4; ++ni)
        acc[mi][ni] = __builtin_amdgcn_mfma_f32_16x16x32_bf16(fa[mi], fb[ni], acc[mi][ni], 0, 0, 0);
  }
#pragma unroll
  for (int mi = 0; mi < 4; ++mi) {
    int grow = m0 + wm * 64 + mi * 16 + kq * 4;
#pragma unroll
    for (int ni = 0; ni < 4; ++ni) {
      int gcol = n0 + wn * 64 + ni * 16 + lr;
      float bv = bias[gcol];
#pragma unroll
      for (int r = 0; r < 4; ++r)
        Cout[(size_t)(grow + r) * N + gcol] = f2bf(acc[mi][ni][r] + bv);
    }
  }
}

// Persistent recurrence, 4 independent batch groups x 64 column-owner WGs.
// h publish = agent-scope atomic exchanges (performed at the MALL — no stale
// dirty L2 lines, no wbl2/inv anywhere). Flags = relaxed agent atomics,
// 128B-strided. Consumers read h with PLAIN loads: hs addresses are fresh
// every step, so consumer L2 lines are cold and miss to the MALL.
__global__ __launch_bounds__(256, 1) void k_recur(
    const ushort* __restrict__ Wh_t,   // [4096][1024] bf16
    const ushort* __restrict__ xi,     // [S*64][4096] bf16 (bh folded in)
    ushort* __restrict__ hs,           // [(S+1)*64][1024] bf16, hs[0]=0
    unsigned* __restrict__ arrive) {   // [4][64*32] strided step counters
  __shared__ alignas(16) ushort Wlds[64 * 1024];   // 128 KiB
  __shared__ alignas(16) ushort htile[16 * 512];   // 16 KiB (one K-half)
  __shared__ alignas(16) float zbuf[4][16][20];    // 5 KiB
  const int grp = blockIdx.x >> 6;      // batch group 0..3
  const int mem = blockIdx.x & 63;      // member in group (column owner)
  const int n0 = mem * 16;
  const int brow0 = grp * 16;
  const int tid = threadIdx.x;
  unsigned* slot = arrive + grp * 64 * 32;   // 32 u32 (128B) stride per member

  // one-time stage of Wh slice, swizzled: unit u = row*128 + (k16 ^ (row&7))
  for (int s = tid; s < 64 * 128; s += 256) {
    int row = s >> 7, k16 = s & 127;
    int g = row >> 4, j = row & 15;
    uint4 v = *(const uint4*)(Wh_t + (size_t)(g * 1024 + n0 + j) * HH + k16 * 8);
    *(uint4*)&Wlds[(row * 128 + (k16 ^ (row & 7))) * 8] = v;
  }
  __syncthreads();

  const int w = tid >> 6, lane = tid & 63;
  const int lr = lane & 15, kq = lane >> 4;
  // h staging: thread owns row srow, 8 contiguous 16B units at k-chunk scol
  const int srow = tid >> 4, scol = tid & 15;
  const int sphase = scol >> 3;                    // which K-half these go to
  ushort* wdst = &htile[((srow * 64) + ((scol & 7) * 8)) * 8];
  const int rx = srow & 7;
  // epilogue (wave 0 only): lane owns (eb, en4..en4+3)
  const int eb = lane >> 2, en4 = (lane & 3) * 4;
  float cr[4] = {0.f, 0.f, 0.f, 0.f};

  for (int t = 0; t < SS; ++t) {
    // ---- load h tile (plain loads; 8 independent -> overlapped) ----
    const ushort* hbase = hs + (size_t)t * BB * HH +
                          (size_t)(brow0 + srow) * HH + scol * 64;
    uint4 hv[8];
#pragma unroll
    for (int i = 0; i < 8; ++i) hv[i] = *(const uint4*)(hbase + i * 8);
    ushort4 xv[4] = {};
    if (w == 0) {   // xi for epilogue: 4 gates x 4 cols (8B each)
      const ushort* xb = xi + ((size_t)t * 64 + brow0 + eb) * G4 + n0 + en4;
#pragma unroll
      for (int g = 0; g < 4; ++g) xv[g] = *(const ushort4*)(xb + (size_t)g * 1024);
    }

    // ---- phase 0: stage K-half 0, compute chunks 0..15 ----
    if (sphase == 0) {
#pragma unroll
      for (int i = 0; i < 8; ++i) *(uint4*)&wdst[(i ^ rx) * 8] = hv[i];
    }
    __syncthreads();
    f32x4 acc0 = {}, acc1 = {};
#pragma unroll
    for (int k = 0; k < 16; k += 2) {
      bf8_t fb0 = *(const bf8_t*)&Wlds[((w * 16 + lr) * 128 + ((k * 4 + kq) ^ (lr & 7))) * 8];
      bf8_t fa0 = *(const bf8_t*)&htile[(lr * 64 + ((k * 4 + kq) ^ (lr & 7))) * 8];
      bf8_t fb1 = *(const bf8_t*)&Wlds[((w * 16 + lr) * 128 + ((k * 4 + 4 + kq) ^ (lr & 7))) * 8];
      bf8_t fa1 = *(const bf8_t*)&htile[(lr * 64 + ((k * 4 + 4 + kq) ^ (lr & 7))) * 8];
      acc0 = __builtin_amdgcn_mfma_f32_16x16x32_bf16(fa0, fb0, acc0, 0, 0, 0);
      acc1 = __builtin_amdgcn_mfma_f32_16x16x32_bf16(fa1, fb1, acc1, 0, 0, 0);
    }
    __syncthreads();

    // ---- phase 1: stage K-half 1, compute chunks 16..31 ----
    if (sphase == 1) {
#pragma unroll
      for (int i = 0; i < 8; ++i) *(uint4*)&wdst[(i ^ rx) * 8] = hv[i];
    }
    __syncthreads();
#pragma unroll
    for (int k = 0; k < 16; k += 2) {
      bf8_t fb0 = *(const bf8_t*)&Wlds[((w * 16 + lr) * 128 + (((16 + k) * 4 + kq) ^ (lr & 7))) * 8];
      bf8_t fa0 = *(const bf8_t*)&htile[(lr * 64 + ((k * 4 + kq) ^ (lr & 7))) * 8];
      bf8_t fb1 = *(const bf8_t*)&Wlds[((w * 16 + lr) * 128 + (((16 + k) * 4 + 4 + kq) ^ (lr & 7))) * 8];
      bf8_t fa1 = *(const bf8_t*)&htile[(lr * 64 + ((k * 4 + 4 + kq) ^ (lr & 7))) * 8];
      acc0 = __builtin_amdgcn_mfma_f32_16x16x32_bf16(fa0, fb0, acc0, 0, 0, 0);
      acc1 = __builtin_amdgcn_mfma_f32_16x16x32_bf16(fa1, fb1, acc1, 0, 0, 0);
    }
#pragma unroll
    for (int r = 0; r < 4; ++r)
      zbuf[w][kq * 4 + r][lr] = acc0[r] + acc1[r];
    __syncthreads();

    // ---- epilogue (wave 0): gates, c update, h publish via MALL atomics ----
    if (w == 0) {
      f32x4 zi4 = *(const f32x4*)&zbuf[0][eb][en4];
      f32x4 zf4 = *(const f32x4*)&zbuf[1][eb][en4];
      f32x4 zg4 = *(const f32x4*)&zbuf[2][eb][en4];
      f32x4 zo4 = *(const f32x4*)&zbuf[3][eb][en4];
      union { unsigned long long u64; ushort u16[4]; } ho;
#pragma unroll
      for (int j = 0; j < 4; ++j) {
        float zi = zi4[j] + bf2f(((const ushort*)&xv[0])[j]);
        float zf = zf4[j] + bf2f(((const ushort*)&xv[1])[j]);
        float zg = zg4[j] + bf2f(((const ushort*)&xv[2])[j]);
        float zo = zo4[j] + bf2f(((const ushort*)&xv[3])[j]);
        float si = 1.f / (1.f + __expf(-zi));
        float sf = 1.f / (1.f + __expf(-zf));
        float tg = tanhf(zg);
        float so = 1.f / (1.f + __expf(-zo));
        float c = sf * cr[j] + si * tg;
        cr[j] = c;
        ho.u16[j] = f2bf(so * tanhf(c));
      }
      // atomic exchange: performed at the coherence point (MALL) — the store
      // is device-visible once retired; no dirty line left in local L2.
      unsigned long long* hdst =
          (unsigned long long*)(hs + (size_t)(t + 1) * BB * HH +
                                (size_t)(brow0 + eb) * HH + n0 + en4);
      unsigned long long old = __hip_atomic_exchange(
          hdst, ho.u64, __ATOMIC_RELAXED, __HIP_MEMORY_SCOPE_AGENT);
      asm volatile("" :: "v"(old));                    // keep the return live
      asm volatile("s_waitcnt vmcnt(0)" ::: "memory"); // performed @ MALL
      if (t + 1 < SS) {
        if (lane == 0)
          __hip_atomic_store(slot + mem * 32, (unsigned)(t + 1),
                             __ATOMIC_RELAXED, __HIP_MEMORY_SCOPE_AGENT);
        // relaxed poll: lane l watches member l (no cache maintenance)
        while (__hip_atomic_load(slot + lane * 32, __ATOMIC_RELAXED,
                                 __HIP_MEMORY_SCOPE_AGENT) < (unsigned)(t + 1))
          __builtin_amdgcn_s_sleep(1);
      }
    }
    __syncthreads();
    // compiler-only ordering: next step's plain h loads must not hoist above
    // the poll. Workgroup acquire = s_waitcnt, no L2 cache maintenance.
    __builtin_amdgcn_fence(__ATOMIC_ACQUIRE, "workgroup");
  }
}

// logits[b][t][a] = hs[t+1][b][:] . Wd_t[a][:] + bd[a]
__global__ __launch_bounds__(256) void k_logits(
    const ushort* __restrict__ hs1, const ushort* __restrict__ Wdt,
    const float* __restrict__ bd, float* __restrict__ out) {
  int gid = blockIdx.x * 256 + threadIdx.x;
  int a = gid & 15, row = gid >> 4;   // row = t*64+b
  int t = row >> 6, b = row & 63;
  const uint4* hp = (const uint4*)(hs1 + (size_t)row * HH);
  const uint4* wp = (const uint4*)(Wdt + (size_t)a * HH);
  float sum = 0.f;
#pragma unroll 4
  for (int i = 0; i < HH / 8; ++i) {
    uint4 hv = hp[i], wv = wp[i];
    const uint* hu = (const uint*)&hv;
    const uint* wu = (const uint*)&wv;
#pragma unroll
    for (int j = 0; j < 4; ++j) {
      sum += bf2f((ushort)(hu[j] & 0xffff)) * bf2f((ushort)(wu[j] & 0xffff));
      sum += bf2f((ushort)(hu[j] >> 16)) * bf2f((ushort)(wu[j] >> 16));
    }
  }
  out[32768 + ((size_t)b * SS + t) * 16 + a] = sum + bd[a];
}

extern "C" void kernel_launch(void* const* d_in, const int* in_sizes, int n_in,
                              void* d_out, int out_size, void* d_ws, size_t ws_size,
                              hipStream_t stream) {
  const int*   x    = (const int*)d_in[0];
  const float* etok = (const float*)d_in[4];
  const float* epos = (const float*)d_in[5];
  const float* Wi   = (const float*)d_in[6];
  const float* Wh   = (const float*)d_in[7];
  const float* bh   = (const float*)d_in[8];
  const float* Wd   = (const float*)d_in[9];
  const float* bd   = (const float*)d_in[10];

  char* ws = (char*)d_ws;
  size_t off = 0;
  ushort* Wi_t = (ushort*)(ws + off); off += (size_t)G4 * HH * 2;            // 8 MB
  ushort* Wh_t = (ushort*)(ws + off); off += (size_t)G4 * HH * 2;            // 8 MB
  ushort* Wd_t = (ushort*)(ws + off); off += 65536;                          // 32 KB (padded)
  ushort* Ae   = (ushort*)(ws + off); off += (size_t)BB * SS * HH * 2;       // 64 MB
  ushort* xi   = (ushort*)(ws + off); off += (size_t)BB * SS * G4 * 2;       // 256 MB
  ushort* hs   = (ushort*)(ws + off); off += (size_t)(SS + 1) * BB * HH * 2; // 64.1 MB
  unsigned* arrive = (unsigned*)(ws + off); off += 4 * 64 * 32 * 4;          // 32 KB

  hipMemsetAsync(d_out, 0, (size_t)out_size * 4, stream);          // dummies = 0
  hipMemsetAsync(hs, 0, (size_t)BB * HH * 2, stream);              // h_0 = 0
  hipMemsetAsync(arrive, 0, 4 * 64 * 32 * 4, stream);              // flag slots

  dim3 b256(256);
  k_transpose_cast<<<dim3(G4 / 32, HH / 32), b256, 0, stream>>>(Wi, Wi_t, HH, G4);
  k_transpose_cast<<<dim3(G4 / 32, HH / 32), b256, 0, stream>>>(Wh, Wh_t, HH, G4);
  k_transpose_cast<<<dim3(1, HH / 32), b256, 0, stream>>>(Wd, Wd_t, HH, 16);
  k_embed<<<BB * SS, b256, 0, stream>>>(x, etok, epos, Ae);
  k_gemm_xi<<<dim3(G4 / 128, BB * SS / 128), b256, 0, stream>>>(Ae, Wi_t, bh, xi, G4);
  k_recur<<<256, b256, 0, stream>>>(Wh_t, xi, hs, arrive);
  k_logits<<<BB * SS * 16 / 256, b256, 0, stream>>>(hs + (size_t)BB * HH, Wd_t, bd,
                                                    (float*)d_out);
}

// Round 7
// 3726.855 us; speedup vs baseline: 2.8318x; 1.1319x over previous
//
#include <hip/hip_runtime.h>
#include <hip/hip_bf16.h>

#define BB 64
#define SS 512
#define HH 1024
#define G4 4096

using bf8_t = __attribute__((ext_vector_type(8))) short;   // 8 bf16 (4 VGPRs)
using f32x4 = __attribute__((ext_vector_type(4))) float;   // 4 fp32 acc

__device__ inline ushort f2bf(float f) {
  __hip_bfloat16 h = __float2bfloat16(f);
  return *reinterpret_cast<ushort*>(&h);
}
__device__ inline float bf2f(ushort u) {
  unsigned v = ((unsigned)u) << 16;
  return __uint_as_float(v);
}

// fp32 [R][C] -> bf16 [C][R]
__global__ __launch_bounds__(256) void k_transpose_cast(
    const float* __restrict__ in, ushort* __restrict__ out, int R, int C) {
  __shared__ float tile[32][33];
  int c0 = blockIdx.x * 32, r0 = blockIdx.y * 32;
  int tx = threadIdx.x & 31, ty = threadIdx.x >> 5;  // 32 x 8
  for (int i = ty; i < 32; i += 8) {
    int r = r0 + i, c = c0 + tx;
    tile[i][tx] = (r < R && c < C) ? in[(size_t)r * C + c] : 0.f;
  }
  __syncthreads();
  for (int i = ty; i < 32; i += 8) {
    int c = c0 + i, r = r0 + tx;
    if (c < C && r < R) out[(size_t)c * R + r] = f2bf(tile[tx][i]);
  }
}

// Ae[row = t*64+b][k] = embed_tok[x[b][t]][k] + embed_pos[t][k], bf16
__global__ __launch_bounds__(256) void k_embed(
    const int* __restrict__ x, const float* __restrict__ etok,
    const float* __restrict__ epos, ushort* __restrict__ Ae) {
  int row = blockIdx.x;
  int t = row >> 6, b = row & 63;
  int tok = x[b * SS + t];
  const float4* tp = (const float4*)(etok + (size_t)tok * HH);
  const float4* pp = (const float4*)(epos + (size_t)t * HH);
  int i = threadIdx.x;  // 256 threads * float4 = 1024
  float4 a = tp[i], p = pp[i];
  ushort4 r = make_ushort4(f2bf(a.x + p.x), f2bf(a.y + p.y),
                           f2bf(a.z + p.z), f2bf(a.w + p.w));
  ((ushort4*)(Ae + (size_t)row * HH))[i] = r;
}

// C[m][n] (bf16) = A[m][k] @ Bt[n][k]^T + bias[n].  M,N mult of 128, K=1024.
__global__ __launch_bounds__(256) void k_gemm_xi(
    const ushort* __restrict__ Ag, const ushort* __restrict__ Bt,
    const float* __restrict__ bias, ushort* __restrict__ Cout, int N) {
  __shared__ alignas(16) ushort As[128 * 40];   // rows padded 32->40 shorts
  __shared__ alignas(16) ushort Bs[128 * 40];
  const int m0 = blockIdx.y * 128, n0 = blockIdx.x * 128;
  const int tid = threadIdx.x;
  const int srow = tid >> 1, shalf = tid & 1;   // stage: 2 thr/row, 16 shorts each
  const int w = tid >> 6, lane = tid & 63;
  const int wm = w >> 1, wn = w & 1;            // 2x2 waves, 64x64 each
  const int lr = lane & 15, kq = lane >> 4;
  f32x4 acc[4][4] = {};
  for (int k0 = 0; k0 < HH; k0 += 32) {
    const uint4* ga = (const uint4*)(Ag + (size_t)(m0 + srow) * HH + k0 + shalf * 16);
    const uint4* gb = (const uint4*)(Bt + (size_t)(n0 + srow) * HH + k0 + shalf * 16);
    uint4 va0 = ga[0], va1 = ga[1];
    uint4 vb0 = gb[0], vb1 = gb[1];
    __syncthreads();
    *(uint4*)&As[srow * 40 + shalf * 16]     = va0;
    *(uint4*)&As[srow * 40 + shalf * 16 + 8] = va1;
    *(uint4*)&Bs[srow * 40 + shalf * 16]     = vb0;
    *(uint4*)&Bs[srow * 40 + shalf * 16 + 8] = vb1;
    __syncthreads();
    bf8_t fa[4], fb[4];
#pragma unroll
    for (int i = 0; i < 4; ++i) {
      fa[i] = *(const bf8_t*)&As[(wm * 64 + i * 16 + lr) * 40 + kq * 8];
      fb[i] = *(const bf8_t*)&Bs[(wn * 64 + i * 16 + lr) * 40 + kq * 8];
    }
#pragma unroll
    for (int mi = 0; mi < 4; ++mi)
#pragma unroll
      for (int ni = 0; ni < 4; ++ni)
        acc[mi][ni] = __builtin_amdgcn_mfma_f32_16x16x32_bf16(fa[mi], fb[ni], acc[mi][ni], 0, 0, 0);
  }
#pragma unroll
  for (int mi = 0; mi < 4; ++mi) {
    int grow = m0 + wm * 64 + mi * 16 + kq * 4;
#pragma unroll
    for (int ni = 0; ni < 4; ++ni) {
      int gcol = n0 + wn * 64 + ni * 16 + lr;
      float bv = bias[gcol];
#pragma unroll
      for (int r = 0; r < 4; ++r)
        Cout[(size_t)(grow + r) * N + gcol] = f2bf(acc[mi][ni][r] + bv);
    }
  }
}

// Persistent recurrence, 4 batch groups x 64 column-owner WGs.
// ALL MFMA operands live in fragment order:
//   unit(k, lane) holds  A[lane&15][k*32 + (lane>>4)*8 .. +8]   (16B)
// fb (Wh) fragment-ordered in LDS once, then held in 128 VGPRs (1 wave/SIMD
// => 512 VGPR budget). h published by producers directly in fragment order
// (8B MALL atomic exchange, r6 transport) + plain row-layout copy for logits.
// Consumer staging = linear 32KB copy -> all LDS accesses conflict-free.
__global__ __launch_bounds__(256, 1) void k_recur(
    const ushort* __restrict__ Wh_t,   // [4096][1024] bf16
    const ushort* __restrict__ xi,     // [S*64][4096] bf16 (bh folded in)
    ushort* __restrict__ hs,           // [(S+1)*64][1024] bf16 row layout
    uint4* __restrict__ fragA,         // [512][4][2048] 16B units: h(t) at t-1
    const uint4* __restrict__ zfrag,   // [4][2048] zeros (h(0))
    unsigned* __restrict__ arrive) {   // [4][64*32] strided step counters
  __shared__ alignas(16) ushort Wlds[8192 * 8];    // 128 KiB fb fragments
  __shared__ alignas(16) ushort htile[1024 * 8];   // 16 KiB: one K-half
  __shared__ alignas(16) float zbuf[4][16][17];    // 4.25 KiB
  const int grp = blockIdx.x >> 6;      // batch group 0..3
  const int mem = blockIdx.x & 63;      // member in group (column owner)
  const int n0 = mem * 16;
  const int brow0 = grp * 16;
  const int tid = threadIdx.x;
  unsigned* slot = arrive + grp * 64 * 32;
  const int w = tid >> 6, lane = tid & 63;

  // one-time: Wh slice into LDS in fragment order (unit = w*2048 + k*64 + lane)
  for (int i = 0; i < 32; ++i) {
    int u = tid + 256 * i;
    int uw = u >> 11, uk = (u >> 6) & 31, ul = u & 63;
    int ukq = ul >> 4, ulr = ul & 15;
    uint4 v = *(const uint4*)(Wh_t + (size_t)(uw * 1024 + n0 + ulr) * HH +
                              uk * 32 + ukq * 8);
    *(uint4*)&Wlds[(size_t)u * 8] = v;
  }
  __syncthreads();

  // fb fragments -> registers, loop-invariant (128 VGPR)
  bf8_t fbr[32];
#pragma unroll
  for (int k = 0; k < 32; ++k)
    fbr[k] = *(const bf8_t*)&Wlds[(w * 2048 + k * 64 + lane) * 8];

  // epilogue ownership (wave 0): batch row eb, cols pc..pc+3
  const int eb = lane >> 2, en4 = (lane & 3) * 4;
  const int pc = n0 + en4;
  const int pk = pc >> 5, pkq = (pc >> 3) & 3;
  const int pubu = pk * 64 + pkq * 16 + eb;     // 16B unit in group block
  const int pubb = (pc & 7) * 2;                // byte offset 0 or 8
  float cr[4] = {0.f, 0.f, 0.f, 0.f};

  for (int t = 0; t < SS; ++t) {
    // ---- fragment-linear h load: 8 consecutive-unit loads per thread ----
    const uint4* fsrc = (t == 0) ? (zfrag + grp * 2048)
                                 : (fragA + ((size_t)(t - 1) * 4 + grp) * 2048);
    uint4 hv[8];
#pragma unroll
    for (int i = 0; i < 8; ++i) hv[i] = fsrc[tid + 256 * i];
    ushort4 xv[4] = {};
    if (w == 0) {   // xi for epilogue: 4 gates x 4 cols (8B each)
      const ushort* xb = xi + ((size_t)t * 64 + brow0 + eb) * G4 + pc;
#pragma unroll
      for (int g = 0; g < 4; ++g) xv[g] = *(const ushort4*)(xb + (size_t)g * 1024);
    }

    f32x4 acc0 = {}, acc1 = {};
    // ---- phase 0: stage K-half 0 (units 0..1023), chunks 0..15 ----
#pragma unroll
    for (int i = 0; i < 4; ++i) *(uint4*)&htile[(tid + 256 * i) * 8] = hv[i];
    __syncthreads();
#pragma unroll
    for (int k = 0; k < 16; k += 2) {
      bf8_t fa0 = *(const bf8_t*)&htile[(k * 64 + lane) * 8];
      bf8_t fa1 = *(const bf8_t*)&htile[((k + 1) * 64 + lane) * 8];
      acc0 = __builtin_amdgcn_mfma_f32_16x16x32_bf16(fa0, fbr[k], acc0, 0, 0, 0);
      acc1 = __builtin_amdgcn_mfma_f32_16x16x32_bf16(fa1, fbr[k + 1], acc1, 0, 0, 0);
    }
    __syncthreads();
    // ---- phase 1: stage K-half 1 (units 1024..2047), chunks 16..31 ----
#pragma unroll
    for (int i = 4; i < 8; ++i) *(uint4*)&htile[(tid + 256 * (i - 4)) * 8] = hv[i];
    __syncthreads();
#pragma unroll
    for (int k = 0; k < 16; k += 2) {
      bf8_t fa0 = *(const bf8_t*)&htile[(k * 64 + lane) * 8];
      bf8_t fa1 = *(const bf8_t*)&htile[((k + 1) * 64 + lane) * 8];
      acc0 = __builtin_amdgcn_mfma_f32_16x16x32_bf16(fa0, fbr[16 + k], acc0, 0, 0, 0);
      acc1 = __builtin_amdgcn_mfma_f32_16x16x32_bf16(fa1, fbr[17 + k], acc1, 0, 0, 0);
    }
#pragma unroll
    for (int r = 0; r < 4; ++r)
      zbuf[w][(lane >> 4) * 4 + r][lane & 15] = acc0[r] + acc1[r];
    __syncthreads();

    // ---- epilogue (wave 0): gates, c update, dual h publish ----
    if (w == 0) {
      f32x4 zi4 = *(const f32x4*)&zbuf[0][eb][en4];
      f32x4 zf4 = *(const f32x4*)&zbuf[1][eb][en4];
      f32x4 zg4 = *(const f32x4*)&zbuf[2][eb][en4];
      f32x4 zo4 = *(const f32x4*)&zbuf[3][eb][en4];
      union { unsigned long long u64; ushort u16[4]; uint2 u32x2; } ho;
#pragma unroll
      for (int j = 0; j < 4; ++j) {
        float zi = zi4[j] + bf2f(((const ushort*)&xv[0])[j]);
        float zf = zf4[j] + bf2f(((const ushort*)&xv[1])[j]);
        float zg = zg4[j] + bf2f(((const ushort*)&xv[2])[j]);
        float zo = zo4[j] + bf2f(((const ushort*)&xv[3])[j]);
        float si = 1.f / (1.f + __expf(-zi));
        float sf = 1.f / (1.f + __expf(-zf));
        float tg = tanhf(zg);
        float so = 1.f / (1.f + __expf(-zo));
        float c = sf * cr[j] + si * tg;
        cr[j] = c;
        ho.u16[j] = f2bf(so * tanhf(c));
      }
      // fragment-order publish: performed at MALL, no dirty L2 line
      unsigned long long* fdst =
          (unsigned long long*)((char*)(fragA + ((size_t)t * 4 + grp) * 2048) +
                                pubu * 16 + pubb);
      unsigned long long old = __hip_atomic_exchange(
          fdst, ho.u64, __ATOMIC_RELAXED, __HIP_MEMORY_SCOPE_AGENT);
      asm volatile("" :: "v"(old));                    // keep return live
      // row-layout copy for k_logits (read only after kernel end)
      *(uint2*)(hs + (size_t)(t + 1) * BB * HH +
                (size_t)(brow0 + eb) * HH + pc) = ho.u32x2;
      asm volatile("s_waitcnt vmcnt(0)" ::: "memory"); // frag performed @ MALL
      if (t + 1 < SS) {
        if (lane == 0)
          __hip_atomic_store(slot + mem * 32, (unsigned)(t + 1),
                             __ATOMIC_RELAXED, __HIP_MEMORY_SCOPE_AGENT);
        while (__hip_atomic_load(slot + lane * 32, __ATOMIC_RELAXED,
                                 __HIP_MEMORY_SCOPE_AGENT) < (unsigned)(t + 1))
          __builtin_amdgcn_s_sleep(1);
      }
    }
    __syncthreads();
    // compiler-only ordering: next step's loads must not hoist above the poll
    __builtin_amdgcn_fence(__ATOMIC_ACQUIRE, "workgroup");
  }
}

// logits[b][t][a] = hs[t+1][b][:] . Wd_t[a][:] + bd[a]
__global__ __launch_bounds__(256) void k_logits(
    const ushort* __restrict__ hs1, const ushort* __restrict__ Wdt,
    const float* __restrict__ bd, float* __restrict__ out) {
  int gid = blockIdx.x * 256 + threadIdx.x;
  int a = gid & 15, row = gid >> 4;   // row = t*64+b
  int t = row >> 6, b = row & 63;
  const uint4* hp = (const uint4*)(hs1 + (size_t)row * HH);
  const uint4* wp = (const uint4*)(Wdt + (size_t)a * HH);
  float sum = 0.f;
#pragma unroll 4
  for (int i = 0; i < HH / 8; ++i) {
    uint4 hv = hp[i], wv = wp[i];
    const uint* hu = (const uint*)&hv;
    const uint* wu = (const uint*)&wv;
#pragma unroll
    for (int j = 0; j < 4; ++j) {
      sum += bf2f((ushort)(hu[j] & 0xffff)) * bf2f((ushort)(wu[j] & 0xffff));
      sum += bf2f((ushort)(hu[j] >> 16)) * bf2f((ushort)(wu[j] >> 16));
    }
  }
  out[32768 + ((size_t)b * SS + t) * 16 + a] = sum + bd[a];
}

extern "C" void kernel_launch(void* const* d_in, const int* in_sizes, int n_in,
                              void* d_out, int out_size, void* d_ws, size_t ws_size,
                              hipStream_t stream) {
  const int*   x    = (const int*)d_in[0];
  const float* etok = (const float*)d_in[4];
  const float* epos = (const float*)d_in[5];
  const float* Wi   = (const float*)d_in[6];
  const float* Wh   = (const float*)d_in[7];
  const float* bh   = (const float*)d_in[8];
  const float* Wd   = (const float*)d_in[9];
  const float* bd   = (const float*)d_in[10];

  char* ws = (char*)d_ws;
  size_t off = 0;
  ushort* Wi_t = (ushort*)(ws + off); off += (size_t)G4 * HH * 2;            // 8 MB
  ushort* Wh_t = (ushort*)(ws + off); off += (size_t)G4 * HH * 2;            // 8 MB
  ushort* Wd_t = (ushort*)(ws + off); off += 65536;                          // 64 KB
  // Ae (64 MB, dead after k_gemm_xi) aliases fragA (64 MB, written by k_recur).
  // Safe: kernel launches begin L2-cold (r1 evidence: per-launch Wh refetch).
  char* AeFrag = ws + off;            off += (size_t)512 * 4 * 2048 * 16;    // 64 MB
  ushort* Ae   = (ushort*)AeFrag;
  uint4*  fragA = (uint4*)AeFrag;
  ushort* xi   = (ushort*)(ws + off); off += (size_t)BB * SS * G4 * 2;       // 256 MB
  ushort* hs   = (ushort*)(ws + off); off += (size_t)(SS + 1) * BB * HH * 2; // 64.1 MB
  uint4*  zfrag = (uint4*)(ws + off); off += (size_t)4 * 2048 * 16;          // 128 KB
  unsigned* arrive = (unsigned*)(ws + off); off += 4 * 64 * 32 * 4;          // 32 KB

  hipMemsetAsync(d_out, 0, (size_t)out_size * 4, stream);          // dummies = 0
  hipMemsetAsync(zfrag, 0, (size_t)4 * 2048 * 16, stream);         // h(0) = 0
  hipMemsetAsync(arrive, 0, 4 * 64 * 32 * 4, stream);              // flag slots

  dim3 b256(256);
  k_transpose_cast<<<dim3(G4 / 32, HH / 32), b256, 0, stream>>>(Wi, Wi_t, HH, G4);
  k_transpose_cast<<<dim3(G4 / 32, HH / 32), b256, 0, stream>>>(Wh, Wh_t, HH, G4);
  k_transpose_cast<<<dim3(1, HH / 32), b256, 0, stream>>>(Wd, Wd_t, HH, 16);
  k_embed<<<BB * SS, b256, 0, stream>>>(x, etok, epos, Ae);
  k_gemm_xi<<<dim3(G4 / 128, BB * SS / 128), b256, 0, stream>>>(Ae, Wi_t, bh, xi, G4);
  k_recur<<<256, b256, 0, stream>>>(Wh_t, xi, hs, fragA, zfrag, arrive);
  k_logits<<<BB * SS * 16 / 256, b256, 0, stream>>>(hs + (size_t)BB * HH, Wd_t, bd,
                                                    (float*)d_out);
}

// Round 8
// 3001.774 us; speedup vs baseline: 3.5159x; 1.2416x over previous
//
#include <hip/hip_runtime.h>
#include <hip/hip_bf16.h>

#define BB 64
#define SS 512
#define HH 1024
#define G4 4096

using bf8_t = __attribute__((ext_vector_type(8))) short;   // 8 bf16 (4 VGPRs)
using f32x4 = __attribute__((ext_vector_type(4))) float;   // 4 fp32 acc

__device__ inline ushort f2bf(float f) {
  __hip_bfloat16 h = __float2bfloat16(f);
  return *reinterpret_cast<ushort*>(&h);
}
__device__ inline float bf2f(ushort u) {
  unsigned v = ((unsigned)u) << 16;
  return __uint_as_float(v);
}

// fp32 [R][C] -> bf16 [C][R]
__global__ __launch_bounds__(256) void k_transpose_cast(
    const float* __restrict__ in, ushort* __restrict__ out, int R, int C) {
  __shared__ float tile[32][33];
  int c0 = blockIdx.x * 32, r0 = blockIdx.y * 32;
  int tx = threadIdx.x & 31, ty = threadIdx.x >> 5;  // 32 x 8
  for (int i = ty; i < 32; i += 8) {
    int r = r0 + i, c = c0 + tx;
    tile[i][tx] = (r < R && c < C) ? in[(size_t)r * C + c] : 0.f;
  }
  __syncthreads();
  for (int i = ty; i < 32; i += 8) {
    int c = c0 + i, r = r0 + tx;
    if (c < C && r < R) out[(size_t)c * R + r] = f2bf(tile[tx][i]);
  }
}

// Ae[row = t*64+b][k] = embed_tok[x[b][t]][k] + embed_pos[t][k], bf16
__global__ __launch_bounds__(256) void k_embed(
    const int* __restrict__ x, const float* __restrict__ etok,
    const float* __restrict__ epos, ushort* __restrict__ Ae) {
  int row = blockIdx.x;
  int t = row >> 6, b = row & 63;
  int tok = x[b * SS + t];
  const float4* tp = (const float4*)(etok + (size_t)tok * HH);
  const float4* pp = (const float4*)(epos + (size_t)t * HH);
  int i = threadIdx.x;  // 256 threads * float4 = 1024
  float4 a = tp[i], p = pp[i];
  ushort4 r = make_ushort4(f2bf(a.x + p.x), f2bf(a.y + p.y),
                           f2bf(a.z + p.z), f2bf(a.w + p.w));
  ((ushort4*)(Ae + (size_t)row * HH))[i] = r;
}

// C[m][n] (bf16) = A[m][k] @ Bt[n][k]^T + bias[n].  M,N mult of 128, K=1024.
__global__ __launch_bounds__(256) void k_gemm_xi(
    const ushort* __restrict__ Ag, const ushort* __restrict__ Bt,
    const float* __restrict__ bias, ushort* __restrict__ Cout, int N) {
  __shared__ alignas(16) ushort As[128 * 40];   // rows padded 32->40 shorts
  __shared__ alignas(16) ushort Bs[128 * 40];
  const int m0 = blockIdx.y * 128, n0 = blockIdx.x * 128;
  const int tid = threadIdx.x;
  const int srow = tid >> 1, shalf = tid & 1;   // stage: 2 thr/row, 16 shorts each
  const int w = tid >> 6, lane = tid & 63;
  const int wm = w >> 1, wn = w & 1;            // 2x2 waves, 64x64 each
  const int lr = lane & 15, kq = lane >> 4;
  f32x4 acc[4][4] = {};
  for (int k0 = 0; k0 < HH; k0 += 32) {
    const uint4* ga = (const uint4*)(Ag + (size_t)(m0 + srow) * HH + k0 + shalf * 16);
    const uint4* gb = (const uint4*)(Bt + (size_t)(n0 + srow) * HH + k0 + shalf * 16);
    uint4 va0 = ga[0], va1 = ga[1];
    uint4 vb0 = gb[0], vb1 = gb[1];
    __syncthreads();
    *(uint4*)&As[srow * 40 + shalf * 16]     = va0;
    *(uint4*)&As[srow * 40 + shalf * 16 + 8] = va1;
    *(uint4*)&Bs[srow * 40 + shalf * 16]     = vb0;
    *(uint4*)&Bs[srow * 40 + shalf * 16 + 8] = vb1;
    __syncthreads();
    bf8_t fa[4], fb[4];
#pragma unroll
    for (int i = 0; i < 4; ++i) {
      fa[i] = *(const bf8_t*)&As[(wm * 64 + i * 16 + lr) * 40 + kq * 8];
      fb[i] = *(const bf8_t*)&Bs[(wn * 64 + i * 16 + lr) * 40 + kq * 8];
    }
#pragma unroll
    for (int mi = 0; mi < 4; ++mi)
#pragma unroll
      for (int ni = 0; ni < 4; ++ni)
        acc[mi][ni] = __builtin_amdgcn_mfma_f32_16x16x32_bf16(fa[mi], fb[ni], acc[mi][ni], 0, 0, 0);
  }
#pragma unroll
  for (int mi = 0; mi < 4; ++mi) {
    int grow = m0 + wm * 64 + mi * 16 + kq * 4;
#pragma unroll
    for (int ni = 0; ni < 4; ++ni) {
      int gcol = n0 + wn * 64 + ni * 16 + lr;
      float bv = bias[gcol];
#pragma unroll
      for (int r = 0; r < 4; ++r)
        Cout[(size_t)(grow + r) * N + gcol] = f2bf(acc[mi][ni][r] + bv);
    }
  }
}

// Persistent recurrence, 4 batch groups x 64 column-owner WGs.
// Fragment order everywhere: unit(k,lane) = A[lane&15][k*32+(lane>>4)*8 ..+8].
// fb (Wh) held in 128 PINNED VGPRs (asm keepalive). Single 32KB htile stage.
// Transport (r6/r7-proven): 8B MALL atomic-exchange publish -> vmcnt(0) ->
// relaxed flag -> relaxed poll -> syncthreads -> workgroup acquire fence.
// Flags contiguous (4 lines/group) so a poll is 4 coalesced transactions.
__global__ __launch_bounds__(256, 1) void k_recur(
    const ushort* __restrict__ Wh_t,   // [4096][1024] bf16
    const ushort* __restrict__ xi,     // [S*64][4096] bf16 (bh folded in)
    ushort* __restrict__ hs,           // [(S+1)*64][1024] bf16 row layout
    uint4* __restrict__ fragA,         // [512][4][2048] 16B units: h(t+1) at t
    const uint4* __restrict__ zfrag,   // [4][2048] zeros (h(0))
    unsigned* __restrict__ arrive) {   // [4][64] contiguous step counters
  __shared__ alignas(16) ushort htile[2048 * 8];   // 32 KiB: full h tile
  __shared__ alignas(16) float zbuf[4][16][17];    // 4.25 KiB
  const int grp = blockIdx.x >> 6;      // batch group 0..3
  const int mem = blockIdx.x & 63;      // member in group (column owner)
  const int n0 = mem * 16;
  const int brow0 = grp * 16;
  const int tid = threadIdx.x;
  unsigned* flags = arrive + grp * 64;
  const int w = tid >> 6, lane = tid & 63;
  const int lr = lane & 15, kq = lane >> 4;

  // one-time: fb fragments direct from global into PINNED registers.
  // fbr[k] = Wh gate w, cols n0..n0+16, k-chunk k  (same mapping as r7 LDS)
  bf8_t fbr[32];
  {
    const ushort* wrow = Wh_t + (size_t)(w * 1024 + n0 + lr) * HH + kq * 8;
#pragma unroll
    for (int k = 0; k < 32; ++k) fbr[k] = *(const bf8_t*)(wrow + k * 32);
#pragma unroll
    for (int k = 0; k < 32; ++k) asm volatile("" : "+v"(fbr[k]));  // pin
  }

  // epilogue ownership (wave 0): batch row eb, cols pc..pc+3
  const int eb = lane >> 2, en4 = (lane & 3) * 4;
  const int pc = n0 + en4;
  const int pk = pc >> 5, pkq = (pc >> 3) & 3;
  const int pubu = pk * 64 + pkq * 16 + eb;     // 16B unit in group block
  const int pubb = (pc & 7) * 2;                // byte offset 0 or 8
  float cr[4] = {0.f, 0.f, 0.f, 0.f};

  // xi(0) preload (wave 0)
  ushort4 xv[4] = {};
  if (w == 0) {
    const ushort* xb = xi + ((size_t)brow0 + eb) * G4 + pc;
#pragma unroll
    for (int g = 0; g < 4; ++g) xv[g] = *(const ushort4*)(xb + (size_t)g * 1024);
  }

  for (int t = 0; t < SS; ++t) {
    // ---- wait for h(t) (t>0): wave0 relaxed-polls 64 contiguous flags ----
    if (t > 0) {
      if (w == 0) {
        while (__hip_atomic_load(flags + lane, __ATOMIC_RELAXED,
                                 __HIP_MEMORY_SCOPE_AGENT) < (unsigned)t)
          __builtin_amdgcn_s_sleep(1);
      }
      __syncthreads();
      __builtin_amdgcn_fence(__ATOMIC_ACQUIRE, "workgroup");  // order hv loads
    }

    // ---- fragment-linear h load: 8 consecutive-unit loads per thread ----
    const uint4* fsrc = (t == 0) ? (zfrag + grp * 2048)
                                 : (fragA + ((size_t)(t - 1) * 4 + grp) * 2048);
    uint4 hv[8];
#pragma unroll
    for (int i = 0; i < 8; ++i) hv[i] = fsrc[tid + 256 * i];

    // ---- stage full 32KB tile, one barrier ----
#pragma unroll
    for (int i = 0; i < 8; ++i) *(uint4*)&htile[(tid + 256 * i) * 8] = hv[i];
    __syncthreads();

    // xi(t+1) prefetch (wave 0) — consumed NEXT step; hidden under MFMA+epi
    ushort4 xn[4] = {};
    if (w == 0) {
      int tn = (t + 1 < SS) ? t + 1 : t;
      const ushort* xb = xi + ((size_t)tn * 64 + brow0 + eb) * G4 + pc;
#pragma unroll
      for (int g = 0; g < 4; ++g) xn[g] = *(const ushort4*)(xb + (size_t)g * 1024);
    }

    // ---- 32 k-chunks straight: fa from LDS (conflict-free), fb pinned regs
    f32x4 acc0 = {}, acc1 = {};
#pragma unroll
    for (int k = 0; k < 32; k += 2) {
      bf8_t fa0 = *(const bf8_t*)&htile[(k * 64 + lane) * 8];
      bf8_t fa1 = *(const bf8_t*)&htile[((k + 1) * 64 + lane) * 8];
      acc0 = __builtin_amdgcn_mfma_f32_16x16x32_bf16(fa0, fbr[k], acc0, 0, 0, 0);
      acc1 = __builtin_amdgcn_mfma_f32_16x16x32_bf16(fa1, fbr[k + 1], acc1, 0, 0, 0);
    }
#pragma unroll
    for (int r = 0; r < 4; ++r)
      zbuf[w][kq * 4 + r][lr] = acc0[r] + acc1[r];
    __syncthreads();

    // ---- epilogue (wave 0): gates, c update, publish, flag, logits copy ----
    if (w == 0) {
      f32x4 zi4 = *(const f32x4*)&zbuf[0][eb][en4];
      f32x4 zf4 = *(const f32x4*)&zbuf[1][eb][en4];
      f32x4 zg4 = *(const f32x4*)&zbuf[2][eb][en4];
      f32x4 zo4 = *(const f32x4*)&zbuf[3][eb][en4];
      union { unsigned long long u64; ushort u16[4]; uint2 u32x2; } ho;
#pragma unroll
      for (int j = 0; j < 4; ++j) {
        float zi = zi4[j] + bf2f(((const ushort*)&xv[0])[j]);
        float zf = zf4[j] + bf2f(((const ushort*)&xv[1])[j]);
        float zg = zg4[j] + bf2f(((const ushort*)&xv[2])[j]);
        float zo = zo4[j] + bf2f(((const ushort*)&xv[3])[j]);
        float si = 1.f / (1.f + __expf(-zi));
        float sf = 1.f / (1.f + __expf(-zf));
        float tg = tanhf(zg);
        float so = 1.f / (1.f + __expf(-zo));
        float c = sf * cr[j] + si * tg;
        cr[j] = c;
        ho.u16[j] = f2bf(so * tanhf(c));
      }
      // fragment-order publish: performed at MALL, no dirty L2 line
      unsigned long long* fdst =
          (unsigned long long*)((char*)(fragA + ((size_t)t * 4 + grp) * 2048) +
                                pubu * 16 + pubb);
      unsigned long long old = __hip_atomic_exchange(
          fdst, ho.u64, __ATOMIC_RELAXED, __HIP_MEMORY_SCOPE_AGENT);
      asm volatile("" :: "v"(old));                    // keep return live
      asm volatile("s_waitcnt vmcnt(0)" ::: "memory"); // frag performed @ MALL
      if (t + 1 < SS && lane == 0)
        __hip_atomic_store(flags + mem, (unsigned)(t + 1),
                           __ATOMIC_RELAXED, __HIP_MEMORY_SCOPE_AGENT);
      // row-layout copy for k_logits — off the critical path (after flag)
      *(uint2*)(hs + (size_t)(t + 1) * BB * HH +
                (size_t)(brow0 + eb) * HH + pc) = ho.u32x2;
      xv[0] = xn[0]; xv[1] = xn[1]; xv[2] = xn[2]; xv[3] = xn[3];
    }
  }
}

// logits[b][t][a] = hs[t+1][b][:] . Wd_t[a][:] + bd[a]
__global__ __launch_bounds__(256) void k_logits(
    const ushort* __restrict__ hs1, const ushort* __restrict__ Wdt,
    const float* __restrict__ bd, float* __restrict__ out) {
  int gid = blockIdx.x * 256 + threadIdx.x;
  int a = gid & 15, row = gid >> 4;   // row = t*64+b
  int t = row >> 6, b = row & 63;
  const uint4* hp = (const uint4*)(hs1 + (size_t)row * HH);
  const uint4* wp = (const uint4*)(Wdt + (size_t)a * HH);
  float sum = 0.f;
#pragma unroll 4
  for (int i = 0; i < HH / 8; ++i) {
    uint4 hv = hp[i], wv = wp[i];
    const uint* hu = (const uint*)&hv;
    const uint* wu = (const uint*)&wv;
#pragma unroll
    for (int j = 0; j < 4; ++j) {
      sum += bf2f((ushort)(hu[j] & 0xffff)) * bf2f((ushort)(wu[j] & 0xffff));
      sum += bf2f((ushort)(hu[j] >> 16)) * bf2f((ushort)(wu[j] >> 16));
    }
  }
  out[32768 + ((size_t)b * SS + t) * 16 + a] = sum + bd[a];
}

extern "C" void kernel_launch(void* const* d_in, const int* in_sizes, int n_in,
                              void* d_out, int out_size, void* d_ws, size_t ws_size,
                              hipStream_t stream) {
  const int*   x    = (const int*)d_in[0];
  const float* etok = (const float*)d_in[4];
  const float* epos = (const float*)d_in[5];
  const float* Wi   = (const float*)d_in[6];
  const float* Wh   = (const float*)d_in[7];
  const float* bh   = (const float*)d_in[8];
  const float* Wd   = (const float*)d_in[9];
  const float* bd   = (const float*)d_in[10];

  char* ws = (char*)d_ws;
  size_t off = 0;
  ushort* Wi_t = (ushort*)(ws + off); off += (size_t)G4 * HH * 2;            // 8 MB
  ushort* Wh_t = (ushort*)(ws + off); off += (size_t)G4 * HH * 2;            // 8 MB
  ushort* Wd_t = (ushort*)(ws + off); off += 65536;                          // 64 KB
  // Ae (64 MB, dead after k_gemm_xi) aliases fragA (64 MB, written by k_recur).
  // Safe: kernel launches begin L2-cold (r1 evidence: per-launch Wh refetch).
  char* AeFrag = ws + off;            off += (size_t)512 * 4 * 2048 * 16;    // 64 MB
  ushort* Ae   = (ushort*)AeFrag;
  uint4*  fragA = (uint4*)AeFrag;
  ushort* xi   = (ushort*)(ws + off); off += (size_t)BB * SS * G4 * 2;       // 256 MB
  ushort* hs   = (ushort*)(ws + off); off += (size_t)(SS + 1) * BB * HH * 2; // 64.1 MB
  uint4*  zfrag = (uint4*)(ws + off); off += (size_t)4 * 2048 * 16;          // 128 KB
  unsigned* arrive = (unsigned*)(ws + off); off += 4 * 64 * 4;               // 1 KB

  hipMemsetAsync(d_out, 0, (size_t)out_size * 4, stream);          // dummies = 0
  hipMemsetAsync(zfrag, 0, (size_t)4 * 2048 * 16, stream);         // h(0) = 0
  hipMemsetAsync(arrive, 0, 4 * 64 * 4, stream);                   // flag slots

  dim3 b256(256);
  k_transpose_cast<<<dim3(G4 / 32, HH / 32), b256, 0, stream>>>(Wi, Wi_t, HH, G4);
  k_transpose_cast<<<dim3(G4 / 32, HH / 32), b256, 0, stream>>>(Wh, Wh_t, HH, G4);
  k_transpose_cast<<<dim3(1, HH / 32), b256, 0, stream>>>(Wd, Wd_t, HH, 16);
  k_embed<<<BB * SS, b256, 0, stream>>>(x, etok, epos, Ae);
  k_gemm_xi<<<dim3(G4 / 128, BB * SS / 128), b256, 0, stream>>>(Ae, Wi_t, bh, xi, G4);
  k_recur<<<256, b256, 0, stream>>>(Wh_t, xi, hs, fragA, zfrag, arrive);
  k_logits<<<BB * SS * 16 / 256, b256, 0, stream>>>(hs + (size_t)BB * HH, Wd_t, bd,
                                                    (float*)d_out);
}